// Round 1
// baseline (386.545 us; speedup 1.0000x reference)
//
#include <hip/hip_runtime.h>

#define B_ 32
#define N_ 1024
#define G_ 2
#define E_ 32
#define M_ (B_*N_)      // 32768
#define NEG 0.01f
#define SCALE (1.0f/32.0f)
#define KT 128
#define QT 128

// ---------------- Kernel 1: grouped QKV projection ----------------
// x: (M, 64); w: (192, 32) rows = [g0: q(32),k(32),v(32); g1: ...]
// out q/k/v: each (B*G, N, E) = (64, 1024, 32)
__global__ __launch_bounds__(256) void qkv_kernel(
    const float* __restrict__ x, const float* __restrict__ w, const float* __restrict__ bias,
    float* __restrict__ q, float* __restrict__ k, float* __restrict__ v)
{
    __shared__ float wsT[32*193];   // transposed + padded: wsT[i*193 + crow]
    __shared__ float bs[192];
    __shared__ float xs[64*64];     // 64 rows of x
    int t = threadIdx.x;
    for (int idx = t; idx < 192*32; idx += 256) {
        int crow = idx >> 5, i = idx & 31;
        wsT[i*193 + crow] = w[idx];
    }
    if (t < 192) bs[t] = bias[t];
    int row0 = blockIdx.x * 64;
    for (int idx = t; idx < 64*64; idx += 256) xs[idx] = x[(size_t)row0*64 + idx];
    __syncthreads();

    int e  = t & 31;
    int r0 = t >> 5;   // 0..7, each thread handles rows r0, r0+8, ..., r0+56
    float acc[8][6];
    #pragma unroll
    for (int r8 = 0; r8 < 8; r8++) {
        acc[r8][0] = bs[e];      acc[r8][1] = bs[32+e];  acc[r8][2] = bs[64+e];
        acc[r8][3] = bs[96+e];   acc[r8][4] = bs[128+e]; acc[r8][5] = bs[160+e];
    }
    for (int i = 0; i < 32; i++) {
        float wv0 = wsT[i*193 + e];
        float wv1 = wsT[i*193 + 32 + e];
        float wv2 = wsT[i*193 + 64 + e];
        float wv3 = wsT[i*193 + 96 + e];
        float wv4 = wsT[i*193 + 128 + e];
        float wv5 = wsT[i*193 + 160 + e];
        #pragma unroll
        for (int r8 = 0; r8 < 8; r8++) {
            int r = r0 + r8*8;
            float x0 = xs[r*64 + i];
            float x1 = xs[r*64 + 32 + i];
            acc[r8][0] += wv0*x0; acc[r8][1] += wv1*x0; acc[r8][2] += wv2*x0;
            acc[r8][3] += wv3*x1; acc[r8][4] += wv4*x1; acc[r8][5] += wv5*x1;
        }
    }
    #pragma unroll
    for (int r8 = 0; r8 < 8; r8++) {
        int r = r0 + r8*8;
        int n = row0 + r;
        int b = n >> 10, nn = n & 1023;
        size_t base0 = (((size_t)(b*2+0))*N_ + nn)*32 + e;
        size_t base1 = (((size_t)(b*2+1))*N_ + nn)*32 + e;
        q[base0] = acc[r8][0]; k[base0] = acc[r8][1]; v[base0] = acc[r8][2];
        q[base1] = acc[r8][3]; k[base1] = acc[r8][4]; v[base1] = acc[r8][5];
    }
}

// ---------------- Kernel 2: fused attention + 3-layer grouped MLP ----------------
struct SmemT {
    union {
        struct { float ks[KT*32]; float vs[KT*32]; } s1;  // 32 KB
        float red[2*QT*36];                                // 36.9 KB (partials, then attn/v)
    } u;
    float wl1[32*65];   // padded weight tiles
    float wl10[32*33];
    float wl11[32*33];
    float bl1[32], bl10[32], bl11[32];
    float linv[QT];
    float hs[QT*33];
};

__global__ __launch_bounds__(256) void attn_mlp_kernel(
    const float* __restrict__ q, const float* __restrict__ k, const float* __restrict__ v,
    const float* __restrict__ w_h1,  const float* __restrict__ b_h1,
    const float* __restrict__ w_h10, const float* __restrict__ b_h10,
    const float* __restrict__ w_h11, const float* __restrict__ b_h11,
    float* __restrict__ out)
{
    __shared__ SmemT sm;
    int t = threadIdx.x;
    int bg = blockIdx.x >> 3;       // 64 (b,g) pairs
    int qtile = blockIdx.x & 7;     // 8 tiles of 128 Q rows
    int b = bg >> 1, g = bg & 1;
    int qbase = qtile * QT;

    // stage MLP weights (padded to break bank conflicts)
    for (int idx = t; idx < 32*64; idx += 256) {
        int o = idx >> 6, i = idx & 63;
        sm.wl1[o*65+i] = w_h1[(g*32+o)*64 + i];
    }
    for (int idx = t; idx < 32*32; idx += 256) {
        int o = idx >> 5, i = idx & 31;
        sm.wl10[o*33+i] = w_h10[(g*32+o)*32 + i];
        sm.wl11[o*33+i] = w_h11[(g*32+o)*32 + i];
    }
    if (t < 32) {
        sm.bl1[t]  = b_h1[g*32+t];
        sm.bl10[t] = b_h10[g*32+t];
        sm.bl11[t] = b_h11[g*32+t];
    }

    int r = t & 127;      // Q row within tile
    int part = t >> 7;    // 0/1: wave-uniform K split
    int n = qbase + r;
    size_t bgN = (size_t)bg * N_;

    float qreg[32];
    {
        const float4* qrow = (const float4*)(q + (bgN + n)*32);
        #pragma unroll
        for (int jj = 0; jj < 8; jj++) {
            float4 f = qrow[jj];
            qreg[jj*4+0] = f.x; qreg[jj*4+1] = f.y; qreg[jj*4+2] = f.z; qreg[jj*4+3] = f.w;
        }
    }

    float l = 0.0f;
    float acc[32];
    #pragma unroll
    for (int e = 0; e < 32; e++) acc[e] = 0.0f;

    for (int kt = 0; kt < N_/KT; kt++) {
        __syncthreads();
        const float4* kg = (const float4*)(k + (bgN + (size_t)kt*KT)*32);
        const float4* vg = (const float4*)(v + (bgN + (size_t)kt*KT)*32);
        float4* ksm = (float4*)sm.u.s1.ks;
        float4* vsm = (float4*)sm.u.s1.vs;
        #pragma unroll
        for (int jj = 0; jj < 4; jj++) {
            ksm[t + jj*256] = kg[t + jj*256];
            vsm[t + jj*256] = vg[t + jj*256];
        }
        __syncthreads();
        // scores are tiny (|s| << 1): softmax without max-subtraction is exact
        for (int j0 = 0; j0 < KT/2; j0++) {
            int j = j0*2 + part;
            const float* kj = &sm.u.s1.ks[j*32];
            float s0=0.f, s1=0.f, s2=0.f, s3=0.f;
            #pragma unroll
            for (int e = 0; e < 32; e += 4) {
                s0 += qreg[e]  *kj[e];   s1 += qreg[e+1]*kj[e+1];
                s2 += qreg[e+2]*kj[e+2]; s3 += qreg[e+3]*kj[e+3];
            }
            float p = __expf(((s0+s1)+(s2+s3)) * SCALE);
            l += p;
            const float* vj = &sm.u.s1.vs[j*32];
            #pragma unroll
            for (int e = 0; e < 32; e++) acc[e] += p * vj[e];
        }
    }
    __syncthreads();
    // write partials (l + acc) to LDS
    {
        float* myred = &sm.u.red[(part*QT + r)*36];
        #pragma unroll
        for (int e = 0; e < 32; e++) myred[e] = acc[e];
        myred[32] = l;
    }
    __syncthreads();
    if (t < QT) {
        float lsum = sm.u.red[t*36+32] + sm.u.red[(QT+t)*36+32];
        sm.linv[t] = 1.0f / lsum;
    }
    __syncthreads();
    // combine partials -> attn in red[0..QT), reload v rows into red[QT..2QT)
    for (int idx = t; idx < QT*32; idx += 256) {
        int rr = idx >> 5, e = idx & 31;
        float a = (sm.u.red[rr*36+e] + sm.u.red[(QT+rr)*36+e]) * sm.linv[rr];
        sm.u.red[rr*36+e] = a;                                   // attn
        sm.u.red[(QT+rr)*36+e] = v[(bgN + qbase + rr)*32 + e];   // v row
    }
    __syncthreads();

    float tmp[QT*32/256];  // 16 staged results per layer
    // layer 1: x_xe = [v(32), attn(32)]
    int cnt = 0;
    for (int idx = t; idx < QT*32; idx += 256, cnt++) {
        int rr = idx >> 5, o = idx & 31;
        float a = sm.bl1[o];
        const float* vrow = &sm.u.red[(QT+rr)*36];
        const float* arow = &sm.u.red[rr*36];
        #pragma unroll
        for (int i = 0; i < 32; i++) a += sm.wl1[o*65+i] * vrow[i];
        #pragma unroll
        for (int i = 0; i < 32; i++) a += sm.wl1[o*65+32+i] * arow[i];
        tmp[cnt] = (a >= 0.f) ? a : NEG*a;
    }
    __syncthreads();
    cnt = 0;
    for (int idx = t; idx < QT*32; idx += 256, cnt++) sm.hs[(idx>>5)*33 + (idx&31)] = tmp[cnt];
    __syncthreads();
    // layer 2
    cnt = 0;
    for (int idx = t; idx < QT*32; idx += 256, cnt++) {
        int rr = idx >> 5, o = idx & 31;
        float a = sm.bl10[o];
        const float* hrow = &sm.hs[rr*33];
        #pragma unroll
        for (int i = 0; i < 32; i++) a += sm.wl10[o*33+i] * hrow[i];
        tmp[cnt] = (a >= 0.f) ? a : NEG*a;
    }
    __syncthreads();
    cnt = 0;
    for (int idx = t; idx < QT*32; idx += 256, cnt++) sm.hs[(idx>>5)*33 + (idx&31)] = tmp[cnt];
    __syncthreads();
    // layer 3 -> global out (M, 64): out[m*64 + g*32 + o]
    cnt = 0;
    for (int idx = t; idx < QT*32; idx += 256, cnt++) {
        int rr = idx >> 5, o = idx & 31;
        float a = sm.bl11[o];
        const float* hrow = &sm.hs[rr*33];
        #pragma unroll
        for (int i = 0; i < 32; i++) a += sm.wl11[o*33+i] * hrow[i];
        a = (a >= 0.f) ? a : NEG*a;
        int nrow = qbase + rr;
        out[((size_t)b*N_ + nrow)*64 + g*32 + o] = a;
    }
}

extern "C" void kernel_launch(void* const* d_in, const int* in_sizes, int n_in,
                              void* d_out, int out_size, void* d_ws, size_t ws_size,
                              hipStream_t stream) {
    const float* x_e   = (const float*)d_in[0];
    const float* w_qkv = (const float*)d_in[1];
    const float* b_qkv = (const float*)d_in[2];
    const float* w_h1  = (const float*)d_in[3];
    const float* b_h1  = (const float*)d_in[4];
    const float* w_h10 = (const float*)d_in[5];
    const float* b_h10 = (const float*)d_in[6];
    const float* w_h11 = (const float*)d_in[7];
    const float* b_h11 = (const float*)d_in[8];
    float* out = (float*)d_out;

    const size_t qkv_elems = (size_t)B_*G_*N_*E_;  // 2,097,152 floats = 8 MB
    float* q = (float*)d_ws;
    float* k = q + qkv_elems;
    float* v = k + qkv_elems;

    hipLaunchKernelGGL(qkv_kernel, dim3(M_/64), dim3(256), 0, stream,
                       x_e, w_qkv, b_qkv, q, k, v);
    hipLaunchKernelGGL(attn_mlp_kernel, dim3(B_*G_*(N_/QT)), dim3(256), 0, stream,
                       q, k, v, w_h1, b_h1, w_h10, b_h10, w_h11, b_h11, out);
}

// Round 2
// 150.080 us; speedup vs baseline: 2.5756x; 2.5756x over previous
//
#include <hip/hip_runtime.h>

#define B_ 32
#define N_ 1024
#define G_ 2
#define E_ 32
#define M_ (B_*N_)
#define NEG 0.01f
#define QT 128
#define KT 128
#define QSC (1.4426950408889634f/32.0f)   // log2(e)/E folded into Q

using half8  = __attribute__((ext_vector_type(8))) _Float16;
using half4  = __attribute__((ext_vector_type(4))) _Float16;
using floatx4 = __attribute__((ext_vector_type(4))) float;

#if defined(__has_builtin)
#if __has_builtin(__builtin_amdgcn_exp2f)
#define EXP2(x) __builtin_amdgcn_exp2f(x)
#endif
#endif
#ifndef EXP2
#define EXP2(x) exp2f(x)
#endif

// ---------------- Kernel 1: grouped QKV projection ----------------
// x: (M,64); w: (192,32). Outputs: Qh,Kh fp16 (bg,n,e) [Q pre-scaled],
// Vth fp16 (bg,e,n) transposed, Vf fp32 (bg,n,e).
__global__ __launch_bounds__(256) void qkv_kernel(
    const float* __restrict__ x, const float* __restrict__ w, const float* __restrict__ bias,
    _Float16* __restrict__ Qh, _Float16* __restrict__ Kh,
    _Float16* __restrict__ Vth, float* __restrict__ Vf)
{
    __shared__ float wsT[32*193];
    __shared__ float bs[192];
    __shared__ float xs[64*64];
    __shared__ _Float16 vsm[64*68];   // [g*32+e][r], stride 68
    int t = threadIdx.x;
    for (int idx = t; idx < 192*32; idx += 256) {
        int crow = idx >> 5, i = idx & 31;
        wsT[i*193 + crow] = w[idx];
    }
    if (t < 192) bs[t] = bias[t];
    int row0 = blockIdx.x * 64;
    for (int idx = t; idx < 64*64; idx += 256) xs[idx] = x[(size_t)row0*64 + idx];
    __syncthreads();

    int e  = t & 31;
    int r0 = t >> 5;
    float acc[8][6];
    #pragma unroll
    for (int r8 = 0; r8 < 8; r8++) {
        acc[r8][0] = bs[e];      acc[r8][1] = bs[32+e];  acc[r8][2] = bs[64+e];
        acc[r8][3] = bs[96+e];   acc[r8][4] = bs[128+e]; acc[r8][5] = bs[160+e];
    }
    for (int i = 0; i < 32; i++) {
        float wv0 = wsT[i*193 + e];
        float wv1 = wsT[i*193 + 32 + e];
        float wv2 = wsT[i*193 + 64 + e];
        float wv3 = wsT[i*193 + 96 + e];
        float wv4 = wsT[i*193 + 128 + e];
        float wv5 = wsT[i*193 + 160 + e];
        #pragma unroll
        for (int r8 = 0; r8 < 8; r8++) {
            int r = r0 + r8*8;
            float x0 = xs[r*64 + i];
            float x1 = xs[r*64 + 32 + i];
            acc[r8][0] += wv0*x0; acc[r8][1] += wv1*x0; acc[r8][2] += wv2*x0;
            acc[r8][3] += wv3*x1; acc[r8][4] += wv4*x1; acc[r8][5] += wv5*x1;
        }
    }
    int b = row0 >> 10, nn0 = row0 & 1023;
    #pragma unroll
    for (int r8 = 0; r8 < 8; r8++) {
        int r = r0 + r8*8;
        int nn = nn0 + r;
        size_t base0 = (((size_t)(b*2+0))*N_ + nn)*32 + e;
        size_t base1 = (((size_t)(b*2+1))*N_ + nn)*32 + e;
        Qh[base0] = (_Float16)(acc[r8][0]*QSC);
        Kh[base0] = (_Float16)acc[r8][1];
        Vf[base0] = acc[r8][2];
        vsm[(0*32+e)*68 + r] = (_Float16)acc[r8][2];
        Qh[base1] = (_Float16)(acc[r8][3]*QSC);
        Kh[base1] = (_Float16)acc[r8][4];
        Vf[base1] = acc[r8][5];
        vsm[(1*32+e)*68 + r] = (_Float16)acc[r8][5];
    }
    __syncthreads();
    // write transposed V: Vth[(b*2+g)*32 + e][nn0 .. nn0+63]
    for (int idx = t; idx < 2*32*16; idx += 256) {
        int g = idx >> 9, rest = idx & 511;
        int ee = rest >> 4, c = rest & 15;
        half4 vv = *(const half4*)&vsm[(g*32+ee)*68 + c*4];
        *(half4*)(Vth + (((size_t)(b*2+g)*32 + ee)*N_ + nn0 + c*4)) = vv;
    }
}

// ---------------- Kernel 2: MFMA attention + MLP ----------------
struct __align__(16) SmemU {
    union {
        struct { _Float16 Kst[128*40]; _Float16 Vtst[32*136]; } a;  // 18.9 KB
        float x[128*68];                                             // 34.8 KB: [v(32) attn(32)] rows
    } u;
    float wl1[32*65];
    float wl10[32*33];
    float wl11[32*33];
    float bl1[32], bl10[32], bl11[32];
    float linv[128];
    float hs[128*33];
};

__global__ __launch_bounds__(256) void attn_mlp_kernel(
    const _Float16* __restrict__ Qh, const _Float16* __restrict__ Kh,
    const _Float16* __restrict__ Vth, const float* __restrict__ Vf,
    const float* __restrict__ w_h1,  const float* __restrict__ b_h1,
    const float* __restrict__ w_h10, const float* __restrict__ b_h10,
    const float* __restrict__ w_h11, const float* __restrict__ b_h11,
    float* __restrict__ out)
{
    __shared__ SmemU sm;
    int t = threadIdx.x;
    int bg = blockIdx.x >> 3;
    int qtile = blockIdx.x & 7;
    int b = bg >> 1, g = bg & 1;
    int qbase = qtile * QT;
    size_t bgN = (size_t)bg * N_;

    // stage MLP weights
    for (int idx = t; idx < 32*64; idx += 256) {
        int o = idx >> 6, i = idx & 63;
        sm.wl1[o*65+i] = w_h1[(g*32+o)*64 + i];
    }
    for (int idx = t; idx < 32*32; idx += 256) {
        int o = idx >> 5, i = idx & 31;
        sm.wl10[o*33+i] = w_h10[(g*32+o)*32 + i];
        sm.wl11[o*33+i] = w_h11[(g*32+o)*32 + i];
    }
    if (t < 32) {
        sm.bl1[t]  = b_h1[g*32+t];
        sm.bl10[t] = b_h10[g*32+t];
        sm.bl11[t] = b_h11[g*32+t];
    }

    int lane = t & 63;
    int w    = t >> 6;          // wave id, handles q rows [q0w, q0w+32)
    int L15  = lane & 15;
    int quad = lane >> 4;
    int q0w  = qbase + w*32;

    // Q B-fragments (held all kernel): B[k=e=quad*8+j][n=q=L15] = Q[q][e]
    half8 bq0 = *(const half8*)(Qh + (bgN + q0w +      L15)*32 + quad*8);
    half8 bq1 = *(const half8*)(Qh + (bgN + q0w + 16 + L15)*32 + quad*8);

    floatx4 o00 = {0.f,0.f,0.f,0.f}, o01 = o00, o10 = o00, o11 = o00;
    float lsum0 = 0.f, lsum1 = 0.f;

    for (int kt = 0; kt < N_/KT; kt++) {
        __syncthreads();
        // stage K tile (128 x 32 f16, row stride 40)
        #pragma unroll
        for (int it = 0; it < 2; it++) {
            int idx = t + it*256;
            int row = idx >> 2, c = idx & 3;
            half8 kv = *(const half8*)(Kh + (bgN + (size_t)kt*KT + row)*32 + c*8);
            *(half8*)&sm.u.a.Kst[row*40 + c*8] = kv;
        }
        // stage Vt tile (32 x 128 f16, row stride 136)
        #pragma unroll
        for (int it = 0; it < 2; it++) {
            int idx = t + it*256;
            int ee = idx >> 4, c = idx & 15;
            half8 vv = *(const half8*)(Vth + (size_t)bg*(32*N_) + (size_t)ee*N_ + kt*KT + c*8);
            *(half8*)&sm.u.a.Vtst[ee*136 + c*8] = vv;
        }
        __syncthreads();

        #pragma unroll
        for (int mt = 0; mt < 8; mt++) {
            // A-frag: K[kpos = mt*16+L15][e = quad*8+j]
            half8 ak = *(const half8*)&sm.u.a.Kst[(mt*16 + L15)*40 + quad*8];
            floatx4 z = {0.f,0.f,0.f,0.f};
            floatx4 s0 = __builtin_amdgcn_mfma_f32_16x16x32_f16(ak, bq0, z, 0, 0, 0);
            floatx4 s1 = __builtin_amdgcn_mfma_f32_16x16x32_f16(ak, bq1, z, 0, 0, 0);
            // p = exp2(s) (scale folded into Q); S^T frag == A-frag of P for 16x16x16
            float p00 = EXP2(s0.x), p01 = EXP2(s0.y), p02 = EXP2(s0.z), p03 = EXP2(s0.w);
            float p10 = EXP2(s1.x), p11 = EXP2(s1.y), p12 = EXP2(s1.z), p13 = EXP2(s1.w);
            lsum0 += (p00+p01)+(p02+p03);
            lsum1 += (p10+p11)+(p12+p13);
            half4 a0 = { (_Float16)p00, (_Float16)p01, (_Float16)p02, (_Float16)p03 };
            half4 a1 = { (_Float16)p10, (_Float16)p11, (_Float16)p12, (_Float16)p13 };
            // B-frags: V[kpos = mt*16+quad*4+j][e = et*16+L15] = Vt[e][kpos]
            half4 bv0 = *(const half4*)&sm.u.a.Vtst[      L15*136 + mt*16 + quad*4];
            half4 bv1 = *(const half4*)&sm.u.a.Vtst[(16+L15)*136 + mt*16 + quad*4];
            o00 = __builtin_amdgcn_mfma_f32_16x16x16f16(a0, bv0, o00, 0, 0, 0);
            o01 = __builtin_amdgcn_mfma_f32_16x16x16f16(a0, bv1, o01, 0, 0, 0);
            o10 = __builtin_amdgcn_mfma_f32_16x16x16f16(a1, bv0, o10, 0, 0, 0);
            o11 = __builtin_amdgcn_mfma_f32_16x16x16f16(a1, bv1, o11, 0, 0, 0);
        }
    }

    // reduce l across quads (kpos partitioned by quad within each 16-block)
    lsum0 += __shfl_xor(lsum0, 16, 64); lsum0 += __shfl_xor(lsum0, 32, 64);
    lsum1 += __shfl_xor(lsum1, 16, 64); lsum1 += __shfl_xor(lsum1, 32, 64);
    if (quad == 0) {
        sm.linv[w*32 +      L15] = 1.0f / lsum0;
        sm.linv[w*32 + 16 + L15] = 1.0f / lsum1;
    }
    __syncthreads();   // linv visible + all k-loop LDS reads done (union reuse)

    // v rows -> x[row][0..31] (fp32 exact)
    for (int idx = t; idx < QT*8; idx += 256) {
        int row = idx >> 3, c = idx & 7;
        float4 f = *(const float4*)(Vf + (bgN + qbase + row)*32 + c*4);
        *(float4*)&sm.u.x[row*68 + c*4] = f;
    }
    // attn -> x[row][32..63]: O frag lane holds O[q=nt*16+quad*4+r][e=et*16+L15]
    {
        const floatx4* ofr[4] = { &o00, &o01, &o10, &o11 };
        #pragma unroll
        for (int nt = 0; nt < 2; nt++) {
            #pragma unroll
            for (int et = 0; et < 2; et++) {
                floatx4 ov = *ofr[nt*2+et];
                #pragma unroll
                for (int r = 0; r < 4; r++) {
                    int row = w*32 + nt*16 + quad*4 + r;
                    float li = sm.linv[row];
                    sm.u.x[row*68 + 32 + et*16 + L15] = ov[r] * li;
                }
            }
        }
    }
    __syncthreads();

    // MLP layer 1: (128 x 64) -> hs (128 x 32)
    for (int idx = t; idx < QT*32; idx += 256) {
        int rr = idx >> 5, o = idx & 31;
        float a = sm.bl1[o];
        const float* xr = &sm.u.x[rr*68];
        #pragma unroll
        for (int i = 0; i < 64; i++) a += sm.wl1[o*65+i] * xr[i];
        sm.hs[rr*33+o] = (a >= 0.f) ? a : NEG*a;
    }
    __syncthreads();
    float tmp[QT*32/256];
    int cnt = 0;
    for (int idx = t; idx < QT*32; idx += 256, cnt++) {
        int rr = idx >> 5, o = idx & 31;
        float a = sm.bl10[o];
        const float* hrow = &sm.hs[rr*33];
        #pragma unroll
        for (int i = 0; i < 32; i++) a += sm.wl10[o*33+i] * hrow[i];
        tmp[cnt] = (a >= 0.f) ? a : NEG*a;
    }
    __syncthreads();
    cnt = 0;
    for (int idx = t; idx < QT*32; idx += 256, cnt++) sm.hs[(idx>>5)*33 + (idx&31)] = tmp[cnt];
    __syncthreads();
    cnt = 0;
    for (int idx = t; idx < QT*32; idx += 256, cnt++) {
        int rr = idx >> 5, o = idx & 31;
        float a = sm.bl11[o];
        const float* hrow = &sm.hs[rr*33];
        #pragma unroll
        for (int i = 0; i < 32; i++) a += sm.wl11[o*33+i] * hrow[i];
        a = (a >= 0.f) ? a : NEG*a;
        out[((size_t)b*N_ + qbase + rr)*64 + g*32 + o] = a;
    }
}

extern "C" void kernel_launch(void* const* d_in, const int* in_sizes, int n_in,
                              void* d_out, int out_size, void* d_ws, size_t ws_size,
                              hipStream_t stream) {
    const float* x_e   = (const float*)d_in[0];
    const float* w_qkv = (const float*)d_in[1];
    const float* b_qkv = (const float*)d_in[2];
    const float* w_h1  = (const float*)d_in[3];
    const float* b_h1  = (const float*)d_in[4];
    const float* w_h10 = (const float*)d_in[5];
    const float* b_h10 = (const float*)d_in[6];
    const float* w_h11 = (const float*)d_in[7];
    const float* b_h11 = (const float*)d_in[8];
    float* out = (float*)d_out;

    const size_t qkv_elems = (size_t)B_*G_*N_*E_;   // 2,097,152
    _Float16* Qh  = (_Float16*)d_ws;
    _Float16* Kh  = Qh + qkv_elems;
    _Float16* Vth = Kh + qkv_elems;
    float*    Vf  = (float*)(Vth + qkv_elems);

    hipLaunchKernelGGL(qkv_kernel, dim3(M_/64), dim3(256), 0, stream,
                       x_e, w_qkv, b_qkv, Qh, Kh, Vth, Vf);
    hipLaunchKernelGGL(attn_mlp_kernel, dim3(B_*G_*(N_/QT)), dim3(256), 0, stream,
                       Qh, Kh, Vth, Vf, w_h1, b_h1, w_h10, b_h10, w_h11, b_h11, out);
}

// Round 3
// 105.720 us; speedup vs baseline: 3.6563x; 1.4196x over previous
//
#include <hip/hip_runtime.h>

#define B_ 32
#define N_ 1024
#define G_ 2
#define E_ 32
#define M_ (B_*N_)
#define NEG 0.01f
#define QT 128
#define KT 128
#define QSC (1.4426950408889634f/32.0f)   // log2(e)/E folded into Q

using half8  = __attribute__((ext_vector_type(8))) _Float16;
using half4  = __attribute__((ext_vector_type(4))) _Float16;
using floatx4 = __attribute__((ext_vector_type(4))) float;

#if defined(__has_builtin)
#if __has_builtin(__builtin_amdgcn_exp2f)
#define EXP2(x) __builtin_amdgcn_exp2f(x)
#endif
#endif
#ifndef EXP2
#define EXP2(x) exp2f(x)
#endif

// ---------------- Kernel 1: MFMA grouped QKV projection ----------------
// x: (M,64) fp32; w: (192,32) fp32. Out[n][o] = sum_i x[n][g*32+i]*Wg[o][i]+b.
// Outputs: Qh,Kh,Vh fp16 (bg,n,e) [Q pre-scaled by QSC], Vth fp16 (bg,e,n).
__global__ __launch_bounds__(256) void qkv_kernel(
    const float* __restrict__ x, const float* __restrict__ w, const float* __restrict__ bias,
    _Float16* __restrict__ Qh, _Float16* __restrict__ Kh,
    _Float16* __restrict__ Vh, _Float16* __restrict__ Vth)
{
    __shared__ _Float16 wsh[192*36];   // padded stride 36 halves (8B-aligned rows, spread banks)
    __shared__ float bsh[192];
    int t = threadIdx.x;
    for (int idx = t; idx < 192*32; idx += 256) {
        int r = idx >> 5, c = idx & 31;
        wsh[r*36 + c] = (_Float16)w[idx];
    }
    if (t < 192) bsh[t] = bias[t];
    __syncthreads();

    int lane = t & 63, wv = t >> 6;
    int L15 = lane & 15, quad = lane >> 4;
    int row0 = blockIdx.x*64 + wv*16;      // wave handles 16 rows
    int b = row0 >> 10, nn0 = row0 & 1023;

    // A-frags: A[m=L15][k=quad*4+j] = x[row0+L15][g*32 + kt*16 + quad*4 + j]
    half4 ax[2][2];
    #pragma unroll
    for (int g2 = 0; g2 < 2; g2++)
        #pragma unroll
        for (int kt = 0; kt < 2; kt++) {
            float4 f = *(const float4*)(x + (size_t)(row0+L15)*64 + g2*32 + kt*16 + quad*4);
            half4 h = { (_Float16)f.x, (_Float16)f.y, (_Float16)f.z, (_Float16)f.w };
            ax[g2][kt] = h;
        }

    floatx4 acc[12];
    #pragma unroll
    for (int i = 0; i < 12; i++) acc[i] = (floatx4){0.f,0.f,0.f,0.f};

    #pragma unroll
    for (int g2 = 0; g2 < 2; g2++)
        #pragma unroll
        for (int nt = 0; nt < 6; nt++)
            #pragma unroll
            for (int kt = 0; kt < 2; kt++) {
                // B[k=quad*4+j][n=L15] = Wg[o=nt*16+L15][i=kt*16+quad*4+j]
                half4 bw = *(const half4*)&wsh[(g2*96+nt*16+L15)*36 + kt*16 + quad*4];
                acc[g2*6+nt] = __builtin_amdgcn_mfma_f32_16x16x16f16(ax[g2][kt], bw, acc[g2*6+nt], 0,0,0);
            }

    // D[m=row=quad*4+reg][n=o=nt*16+L15]
    #pragma unroll
    for (int g2 = 0; g2 < 2; g2++) {
        size_t bg = (size_t)(b*2 + g2);
        #pragma unroll
        for (int nt = 0; nt < 6; nt++) {
            float bia = bsh[g2*96 + nt*16 + L15];
            floatx4 a4 = acc[g2*6+nt];
            int e = (nt & 1)*16 + L15;
            int kind = nt >> 1;   // 0:q 1:k 2:v
            if (kind == 0) {
                #pragma unroll
                for (int r = 0; r < 4; r++) {
                    int nn = nn0 + quad*4 + r;
                    Qh[(bg*N_ + nn)*32 + e] = (_Float16)((a4[r] + bia)*QSC);
                }
            } else if (kind == 1) {
                #pragma unroll
                for (int r = 0; r < 4; r++) {
                    int nn = nn0 + quad*4 + r;
                    Kh[(bg*N_ + nn)*32 + e] = (_Float16)(a4[r] + bia);
                }
            } else {
                half4 vv;
                #pragma unroll
                for (int r = 0; r < 4; r++) {
                    int nn = nn0 + quad*4 + r;
                    float vval = a4[r] + bia;
                    Vh[(bg*N_ + nn)*32 + e] = (_Float16)vval;
                    vv[r] = (_Float16)vval;
                }
                *(half4*)(Vth + (bg*32 + e)*N_ + nn0 + quad*4) = vv;
            }
        }
    }
}

// ---------------- Kernel 2: MFMA attention + MFMA MLP ----------------
struct __align__(16) SmemU {
    union {
        struct { _Float16 Kst[128*40]; _Float16 Vtst[32*136]; } a;  // 18.9 KB
        _Float16 xs[128*72];   // [q][ v(32) | attn(32) ] fp16, stride 72
    } u;
    float linv[128];
    float bl1[32], bl10[32], bl11[32];
};

__global__ __launch_bounds__(256) void attn_mlp_kernel(
    const _Float16* __restrict__ Qh, const _Float16* __restrict__ Kh,
    const _Float16* __restrict__ Vh, const _Float16* __restrict__ Vth,
    const float* __restrict__ w_h1,  const float* __restrict__ b_h1,
    const float* __restrict__ w_h10, const float* __restrict__ b_h10,
    const float* __restrict__ w_h11, const float* __restrict__ b_h11,
    float* __restrict__ out)
{
    __shared__ SmemU sm;
    int t = threadIdx.x;
    int bg = blockIdx.x >> 3;
    int qtile = blockIdx.x & 7;
    int b = bg >> 1, g = bg & 1;
    int qbase = qtile * QT;
    size_t bgN = (size_t)bg * N_;

    if (t < 32) {
        sm.bl1[t]  = b_h1[g*32+t];
        sm.bl10[t] = b_h10[g*32+t];
        sm.bl11[t] = b_h11[g*32+t];
    }

    int lane = t & 63;
    int w    = t >> 6;
    int L15  = lane & 15;
    int quad = lane >> 4;
    int q0w  = qbase + w*32;

    // Q B-fragments: B[k=e=quad*8+j][n=q=L15]
    half8 bq0 = *(const half8*)(Qh + (bgN + q0w +      L15)*32 + quad*8);
    half8 bq1 = *(const half8*)(Qh + (bgN + q0w + 16 + L15)*32 + quad*8);

    floatx4 o00 = {0.f,0.f,0.f,0.f}, o01 = o00, o10 = o00, o11 = o00;
    float lsum0 = 0.f, lsum1 = 0.f;

    for (int kt = 0; kt < N_/KT; kt++) {
        __syncthreads();
        #pragma unroll
        for (int it = 0; it < 2; it++) {
            int idx = t + it*256;
            int row = idx >> 2, c = idx & 3;
            half8 kv = *(const half8*)(Kh + (bgN + (size_t)kt*KT + row)*32 + c*8);
            *(half8*)&sm.u.a.Kst[row*40 + c*8] = kv;
        }
        #pragma unroll
        for (int it = 0; it < 2; it++) {
            int idx = t + it*256;
            int ee = idx >> 4, c = idx & 15;
            half8 vv = *(const half8*)(Vth + (size_t)bg*(32*N_) + (size_t)ee*N_ + kt*KT + c*8);
            *(half8*)&sm.u.a.Vtst[ee*136 + c*8] = vv;
        }
        __syncthreads();

        #pragma unroll
        for (int mt = 0; mt < 8; mt++) {
            half8 ak = *(const half8*)&sm.u.a.Kst[(mt*16 + L15)*40 + quad*8];
            floatx4 z = {0.f,0.f,0.f,0.f};
            floatx4 s0 = __builtin_amdgcn_mfma_f32_16x16x32_f16(ak, bq0, z, 0, 0, 0);
            floatx4 s1 = __builtin_amdgcn_mfma_f32_16x16x32_f16(ak, bq1, z, 0, 0, 0);
            float p00 = EXP2(s0.x), p01 = EXP2(s0.y), p02 = EXP2(s0.z), p03 = EXP2(s0.w);
            float p10 = EXP2(s1.x), p11 = EXP2(s1.y), p12 = EXP2(s1.z), p13 = EXP2(s1.w);
            lsum0 += (p00+p01)+(p02+p03);
            lsum1 += (p10+p11)+(p12+p13);
            half4 a0 = { (_Float16)p00, (_Float16)p01, (_Float16)p02, (_Float16)p03 };
            half4 a1 = { (_Float16)p10, (_Float16)p11, (_Float16)p12, (_Float16)p13 };
            half4 bv0 = *(const half4*)&sm.u.a.Vtst[      L15*136 + mt*16 + quad*4];
            half4 bv1 = *(const half4*)&sm.u.a.Vtst[(16+L15)*136 + mt*16 + quad*4];
            o00 = __builtin_amdgcn_mfma_f32_16x16x16f16(a0, bv0, o00, 0, 0, 0);
            o01 = __builtin_amdgcn_mfma_f32_16x16x16f16(a0, bv1, o01, 0, 0, 0);
            o10 = __builtin_amdgcn_mfma_f32_16x16x16f16(a1, bv0, o10, 0, 0, 0);
            o11 = __builtin_amdgcn_mfma_f32_16x16x16f16(a1, bv1, o11, 0, 0, 0);
        }
    }

    lsum0 += __shfl_xor(lsum0, 16, 64); lsum0 += __shfl_xor(lsum0, 32, 64);
    lsum1 += __shfl_xor(lsum1, 16, 64); lsum1 += __shfl_xor(lsum1, 32, 64);
    if (quad == 0) {
        sm.linv[w*32 +      L15] = 1.0f / lsum0;
        sm.linv[w*32 + 16 + L15] = 1.0f / lsum1;
    }
    __syncthreads();   // linv visible; all K-loop LDS reads done (union reuse)

    // build xs: v part (coalesced fp16 copy)
    for (int idx = t; idx < 512; idx += 256) {
        int row = idx >> 2, c = idx & 3;
        half8 vv = *(const half8*)(Vh + (bgN + qbase + row)*32 + c*8);
        *(half8*)&sm.u.xs[row*72 + c*8] = vv;
    }
    // attn part: O frag lane holds O[q=w*32+nt*16+quad*4+r][e=et*16+L15]
    {
        const floatx4* ofr[2][2] = { {&o00,&o01}, {&o10,&o11} };
        #pragma unroll
        for (int nt = 0; nt < 2; nt++) {
            float4 li = *(const float4*)&sm.linv[w*32 + nt*16 + quad*4];
            #pragma unroll
            for (int et = 0; et < 2; et++) {
                floatx4 ov = *ofr[nt][et];
                sm.u.xs[(w*32+nt*16+quad*4+0)*72 + 32 + et*16 + L15] = (_Float16)(ov[0]*li.x);
                sm.u.xs[(w*32+nt*16+quad*4+1)*72 + 32 + et*16 + L15] = (_Float16)(ov[1]*li.y);
                sm.u.xs[(w*32+nt*16+quad*4+2)*72 + 32 + et*16 + L15] = (_Float16)(ov[2]*li.z);
                sm.u.xs[(w*32+nt*16+quad*4+3)*72 + 32 + et*16 + L15] = (_Float16)(ov[3]*li.w);
            }
        }
    }
    __syncthreads();

    // weight A-frags: A[m=L15][k=quad*4+j]
    half4 a1f[2][4], a2f[2][2], a3f[2][2];
    #pragma unroll
    for (int mt = 0; mt < 2; mt++) {
        #pragma unroll
        for (int kt = 0; kt < 4; kt++) {
            float4 f = *(const float4*)(w_h1 + (size_t)(g*32+mt*16+L15)*64 + kt*16 + quad*4);
            half4 h = { (_Float16)f.x, (_Float16)f.y, (_Float16)f.z, (_Float16)f.w };
            a1f[mt][kt] = h;
        }
        #pragma unroll
        for (int kt = 0; kt < 2; kt++) {
            float4 f = *(const float4*)(w_h10 + (size_t)(g*32+mt*16+L15)*32 + kt*16 + quad*4);
            half4 h = { (_Float16)f.x, (_Float16)f.y, (_Float16)f.z, (_Float16)f.w };
            a2f[mt][kt] = h;
            float4 f2 = *(const float4*)(w_h11 + (size_t)(g*32+mt*16+L15)*32 + kt*16 + quad*4);
            half4 h2 = { (_Float16)f2.x, (_Float16)f2.y, (_Float16)f2.z, (_Float16)f2.w };
            a3f[mt][kt] = h2;
        }
    }

    // layer 1: D[o][q] = sum_i W1[o][i] * x[q][i]
    floatx4 d1[2][2];
    #pragma unroll
    for (int mt = 0; mt < 2; mt++)
        #pragma unroll
        for (int nt = 0; nt < 2; nt++) d1[mt][nt] = (floatx4){0.f,0.f,0.f,0.f};
    #pragma unroll
    for (int nt = 0; nt < 2; nt++)
        #pragma unroll
        for (int kt = 0; kt < 4; kt++) {
            // B[k=quad*4+j][n=L15] = x[q=w*32+nt*16+L15][i=kt*16+quad*4+j]
            half4 b1 = *(const half4*)&sm.u.xs[(w*32+nt*16+L15)*72 + kt*16 + quad*4];
            d1[0][nt] = __builtin_amdgcn_mfma_f32_16x16x16f16(a1f[0][kt], b1, d1[0][nt], 0,0,0);
            d1[1][nt] = __builtin_amdgcn_mfma_f32_16x16x16f16(a1f[1][kt], b1, d1[1][nt], 0,0,0);
        }
    // bias + leaky -> B-frags of layer 2 (C layout == B layout, in-register chain)
    half4 h1b[2][2];
    #pragma unroll
    for (int mt = 0; mt < 2; mt++) {
        float4 bb = *(const float4*)&sm.bl1[mt*16 + quad*4];
        #pragma unroll
        for (int nt = 0; nt < 2; nt++) {
            float v0 = d1[mt][nt][0] + bb.x; v0 = (v0>=0.f)?v0:NEG*v0;
            float v1 = d1[mt][nt][1] + bb.y; v1 = (v1>=0.f)?v1:NEG*v1;
            float v2 = d1[mt][nt][2] + bb.z; v2 = (v2>=0.f)?v2:NEG*v2;
            float v3 = d1[mt][nt][3] + bb.w; v3 = (v3>=0.f)?v3:NEG*v3;
            half4 h = { (_Float16)v0, (_Float16)v1, (_Float16)v2, (_Float16)v3 };
            h1b[mt][nt] = h;
        }
    }
    // layer 2
    floatx4 d2[2][2];
    #pragma unroll
    for (int mt = 0; mt < 2; mt++)
        #pragma unroll
        for (int nt = 0; nt < 2; nt++) d2[mt][nt] = (floatx4){0.f,0.f,0.f,0.f};
    #pragma unroll
    for (int mt = 0; mt < 2; mt++)
        #pragma unroll
        for (int nt = 0; nt < 2; nt++)
            #pragma unroll
            for (int kt = 0; kt < 2; kt++)
                d2[mt][nt] = __builtin_amdgcn_mfma_f32_16x16x16f16(a2f[mt][kt], h1b[kt][nt], d2[mt][nt], 0,0,0);
    half4 h2b[2][2];
    #pragma unroll
    for (int mt = 0; mt < 2; mt++) {
        float4 bb = *(const float4*)&sm.bl10[mt*16 + quad*4];
        #pragma unroll
        for (int nt = 0; nt < 2; nt++) {
            float v0 = d2[mt][nt][0] + bb.x; v0 = (v0>=0.f)?v0:NEG*v0;
            float v1 = d2[mt][nt][1] + bb.y; v1 = (v1>=0.f)?v1:NEG*v1;
            float v2 = d2[mt][nt][2] + bb.z; v2 = (v2>=0.f)?v2:NEG*v2;
            float v3 = d2[mt][nt][3] + bb.w; v3 = (v3>=0.f)?v3:NEG*v3;
            half4 h = { (_Float16)v0, (_Float16)v1, (_Float16)v2, (_Float16)v3 };
            h2b[mt][nt] = h;
        }
    }
    // layer 3 + store
    floatx4 d3[2][2];
    #pragma unroll
    for (int mt = 0; mt < 2; mt++)
        #pragma unroll
        for (int nt = 0; nt < 2; nt++) d3[mt][nt] = (floatx4){0.f,0.f,0.f,0.f};
    #pragma unroll
    for (int mt = 0; mt < 2; mt++)
        #pragma unroll
        for (int nt = 0; nt < 2; nt++)
            #pragma unroll
            for (int kt = 0; kt < 2; kt++)
                d3[mt][nt] = __builtin_amdgcn_mfma_f32_16x16x16f16(a3f[mt][kt], h2b[kt][nt], d3[mt][nt], 0,0,0);
    #pragma unroll
    for (int mt = 0; mt < 2; mt++) {
        float4 bb = *(const float4*)&sm.bl11[mt*16 + quad*4];
        #pragma unroll
        for (int nt = 0; nt < 2; nt++) {
            size_t rowbase = ((size_t)b*N_ + qbase + w*32 + nt*16 + L15)*64 + g*32 + mt*16 + quad*4;
            float v0 = d3[mt][nt][0] + bb.x; out[rowbase+0] = (v0>=0.f)?v0:NEG*v0;
            float v1 = d3[mt][nt][1] + bb.y; out[rowbase+1] = (v1>=0.f)?v1:NEG*v1;
            float v2 = d3[mt][nt][2] + bb.z; out[rowbase+2] = (v2>=0.f)?v2:NEG*v2;
            float v3 = d3[mt][nt][3] + bb.w; out[rowbase+3] = (v3>=0.f)?v3:NEG*v3;
        }
    }
}

extern "C" void kernel_launch(void* const* d_in, const int* in_sizes, int n_in,
                              void* d_out, int out_size, void* d_ws, size_t ws_size,
                              hipStream_t stream) {
    const float* x_e   = (const float*)d_in[0];
    const float* w_qkv = (const float*)d_in[1];
    const float* b_qkv = (const float*)d_in[2];
    const float* w_h1  = (const float*)d_in[3];
    const float* b_h1  = (const float*)d_in[4];
    const float* w_h10 = (const float*)d_in[5];
    const float* b_h10 = (const float*)d_in[6];
    const float* w_h11 = (const float*)d_in[7];
    const float* b_h11 = (const float*)d_in[8];
    float* out = (float*)d_out;

    const size_t qkv_elems = (size_t)B_*G_*N_*E_;   // 2,097,152
    _Float16* Qh  = (_Float16*)d_ws;
    _Float16* Kh  = Qh + qkv_elems;
    _Float16* Vh  = Kh + qkv_elems;
    _Float16* Vth = Vh + qkv_elems;

    hipLaunchKernelGGL(qkv_kernel, dim3(M_/64), dim3(256), 0, stream,
                       x_e, w_qkv, b_qkv, Qh, Kh, Vh, Vth);
    hipLaunchKernelGGL(attn_mlp_kernel, dim3(B_*G_*(N_/QT)), dim3(256), 0, stream,
                       Qh, Kh, Vh, Vth, w_h1, b_h1, w_h10, b_h10, w_h11, b_h11, out);
}